// Round 7
// baseline (556.645 us; speedup 1.0000x reference)
//
#include <hip/hip_runtime.h>

typedef __attribute__((ext_vector_type(4))) unsigned short u16x4;
typedef __attribute__((ext_vector_type(8))) short short8;
typedef __attribute__((ext_vector_type(4))) short short4b;
typedef __attribute__((ext_vector_type(4))) float f32x4;

__device__ inline unsigned short f2bf(float f) {
    union { float f; unsigned int i; } v; v.f = f;
    unsigned int r = v.i + 0x7fffu + ((v.i >> 16) & 1u);
    return (unsigned short)(r >> 16);
}

#define MFMA_PV(a, b, c) __builtin_amdgcn_mfma_f32_16x16x16bf16_1k((a), (b), (c), 0, 0, 0)
#define MFMA32(a, b, c) __builtin_amdgcn_mfma_f32_16x16x32_bf16((a), (b), (c), 0, 0, 0)

// exp(s*0.125) == exp2(s * 0.125*log2(e))
#define SEXP(s) exp2f((s) * 0.18033688011112042f)

__device__ inline void gload_lds16(const unsigned short* g, unsigned short* l) {
    __builtin_amdgcn_global_load_lds(
        (const __attribute__((address_space(1))) void*)g,
        (__attribute__((address_space(3))) void*)l,
        16, 0, 0);
}

// ---------------------------------------------------------------------------
// prep: 3 input converts (f32->bf16) + 4 weight transpose+converts, one launch
// grid: 24576 convert blocks + 4096 transpose blocks = 28672
// ---------------------------------------------------------------------------
__global__ __launch_bounds__(256) void prep(const float* __restrict__ q,
                                            const float* __restrict__ k,
                                            const float* __restrict__ v,
                                            const float* __restrict__ W0,
                                            const float* __restrict__ W1,
                                            const float* __restrict__ W2,
                                            const float* __restrict__ W3,
                                            unsigned short* __restrict__ Xq,
                                            unsigned short* __restrict__ Xk,
                                            unsigned short* __restrict__ Xv,
                                            unsigned short* __restrict__ O0,
                                            unsigned short* __restrict__ O1,
                                            unsigned short* __restrict__ O2,
                                            unsigned short* __restrict__ O3) {
    __shared__ unsigned short tile[32][33];
    int bid = blockIdx.x;
    if (bid < 24576) {
        const float* in = (bid < 8192) ? q : (bid < 16384) ? k : v;
        unsigned short* out = (bid < 8192) ? Xq : (bid < 16384) ? Xk : Xv;
        int i = (bid & 8191) * 256 + threadIdx.x;
        float4 vv = ((const float4*)in)[i];
        u16x4 o = { f2bf(vv.x), f2bf(vv.y), f2bf(vv.z), f2bf(vv.w) };
        ((u16x4*)out)[i] = o;
    } else {
        int rem = bid - 24576;
        int z = rem >> 10, idx = rem & 1023;
        const float* in = (z == 0) ? W0 : (z == 1) ? W1 : (z == 2) ? W2 : W3;
        unsigned short* out = (z == 0) ? O0 : (z == 1) ? O1 : (z == 2) ? O2 : O3;
        int c0 = (idx & 31) * 32, r0 = (idx >> 5) * 32;
        int x = threadIdx.x & 31, y = threadIdx.x >> 5;
#pragma unroll
        for (int i = 0; i < 4; i++)
            tile[y + i * 8][x] = f2bf(in[(size_t)(r0 + y + i * 8) * 1024 + c0 + x]);
        __syncthreads();
#pragma unroll
        for (int i = 0; i < 4; i++)
            out[(size_t)(c0 + y + i * 8) * 1024 + r0 + x] = tile[x][y + i * 8];
    }
}

// ---------------------------------------------------------------------------
// Shared GEMM core (m97 structure + T2 via pre-swizzled source).
// acc[i][j] += X-tile * Wt-tile over K. LDS linear [128][64], bank swizzle
// baked by pre-swizzling the GLOBAL source chunk.
// ---------------------------------------------------------------------------
__device__ __forceinline__ void gemm_core(const unsigned short* __restrict__ X,
                                          const unsigned short* __restrict__ Wt,
                                          unsigned short* As, unsigned short* Bs,
                                          int m0, int n0, int K, f32x4 acc[4][4]) {
    const int t = threadIdx.x;
    const int l = t & 63, w = t >> 6;
    const int lg = l >> 4, ln = l & 15;
    const int wm = (w >> 1) * 64, wn = (w & 1) * 64;

    int sr[4], sc[4];
#pragma unroll
    for (int i = 0; i < 4; i++) {
        int pos = i * 2048 + t * 8;
        sr[i] = pos >> 6;
        int c8 = (pos >> 3) & 7;
        sc[i] = (c8 ^ (sr[i] & 7)) * 8;
    }

    for (int k0 = 0; k0 < K; k0 += 64) {
#pragma unroll
        for (int i = 0; i < 4; i++)
            gload_lds16(&X[(size_t)(m0 + sr[i]) * K + k0 + sc[i]], &As[i * 2048 + w * 512]);
#pragma unroll
        for (int i = 0; i < 4; i++)
            gload_lds16(&Wt[(size_t)(n0 + sr[i]) * K + k0 + sc[i]], &Bs[i * 2048 + w * 512]);
        __syncthreads();
#pragma unroll
        for (int kk = 0; kk < 2; kk++) {
            short8 af[4], bfr[4];
#pragma unroll
            for (int i = 0; i < 4; i++) {
                int sl = (((kk << 2) | lg) ^ (ln & 7)) * 8;
                af[i]  = *(const short8*)&As[(wm + i * 16 + ln) * 64 + sl];
                bfr[i] = *(const short8*)&Bs[(wn + i * 16 + ln) * 64 + sl];
            }
#pragma unroll
            for (int i = 0; i < 4; i++)
#pragma unroll
                for (int j = 0; j < 4; j++)
                    acc[i][j] = MFMA32(af[i], bfr[j], acc[i][j]);
        }
        __syncthreads();
    }
}

// ---------------------------------------------------------------------------
// Q-GEMM (z=0, linear bf16 out) + K-GEMM (z=1, KTILED+swizzle out), one launch
// grid (8, 64, 2)
// ---------------------------------------------------------------------------
__global__ __launch_bounds__(256) void gemm_qk(const unsigned short* __restrict__ Xq,
                                               const unsigned short* __restrict__ Xk,
                                               const unsigned short* __restrict__ WqT,
                                               const unsigned short* __restrict__ WkT,
                                               const float* __restrict__ bq,
                                               const float* __restrict__ bk,
                                               unsigned short* __restrict__ Qp,
                                               unsigned short* __restrict__ Kt) {
    __shared__ unsigned short As[8192];
    __shared__ unsigned short Bs[8192];
    const int z = blockIdx.z;
    const unsigned short* X = z ? Xk : Xq;
    const unsigned short* Wt = z ? WkT : WqT;
    const float* bias = z ? bk : bq;
    const int t = threadIdx.x, l = t & 63, w = t >> 6;
    const int lg = l >> 4, ln = l & 15;
    const int wm = (w >> 1) * 64, wn = (w & 1) * 64;
    const int m0 = blockIdx.y * 128, n0 = blockIdx.x * 128;

    const f32x4 zero = {0.f, 0.f, 0.f, 0.f};
    f32x4 acc[4][4];
#pragma unroll
    for (int i = 0; i < 4; i++)
#pragma unroll
        for (int j = 0; j < 4; j++) acc[i][j] = zero;

    gemm_core(X, Wt, As, Bs, m0, n0, 1024, acc);

#pragma unroll
    for (int j = 0; j < 4; j++) {
        int gn = n0 + wn + j * 16 + ln;
        float bvv = bias[gn];
#pragma unroll
        for (int i = 0; i < 4; i++) {
            int gm = m0 + wm + i * 16 + 4 * lg;
#pragma unroll
            for (int jj = 0; jj < 4; jj++) {
                float val = acc[i][j][jj] + bvv;
                int m = gm + jj, n = gn;
                if (z) {
                    int b = m >> 11, s = m & 2047;
                    int itk = s >> 5, r = s & 31;
                    int h = n >> 6, dl = n & 63;
                    int cst = (dl >> 3) ^ (r & 7);
                    size_t off = (size_t)(b * 16 + h) * 131072 +
                                 (size_t)itk * 2048 + r * 64 + cst * 8 + (dl & 7);
                    Kt[off] = f2bf(val);
                } else {
                    Qp[(size_t)m * 1024 + n] = f2bf(val);
                }
            }
        }
    }
}

// ---------------------------------------------------------------------------
// Heterogeneous launch: blocks 0..1023 = attn pass1 (softmax denominators),
// blocks 1024..1535 = V-GEMM with VTILED epilogue. Independent work, overlaps
// VALU-bound pass1 with memory/MFMA-bound GEMM.
// ---------------------------------------------------------------------------
__global__ __launch_bounds__(256) void gemmv_pass1(const unsigned short* __restrict__ Xv,
                                                   const unsigned short* __restrict__ WvT,
                                                   const float* __restrict__ bv,
                                                   unsigned short* __restrict__ Vt,
                                                   const unsigned short* __restrict__ Qp,
                                                   const unsigned short* __restrict__ Kt,
                                                   float* __restrict__ se_buf) {
    const int S = 2048, Dm = 1024;
    __shared__ unsigned short smem[16384];   // pass1: Ks[2][4096]; gemm: As+Bs

    int bid = blockIdx.x;
    int t = threadIdx.x, l = t & 63, w = t >> 6;
    int lg = l >> 4, ln = l & 15;

    if (bid >= 1024) {
        // ---------------- V-GEMM ----------------
        int g = bid - 1024;
        const int wm = (w >> 1) * 64, wn = (w & 1) * 64;
        const int m0 = (g >> 3) * 128, n0 = (g & 7) * 128;
        const f32x4 zero = {0.f, 0.f, 0.f, 0.f};
        f32x4 acc[4][4];
#pragma unroll
        for (int i = 0; i < 4; i++)
#pragma unroll
            for (int j = 0; j < 4; j++) acc[i][j] = zero;

        gemm_core(Xv, WvT, smem, smem + 8192, m0, n0, 1024, acc);

#pragma unroll
        for (int j = 0; j < 4; j++) {
            int gn = n0 + wn + j * 16 + ln;
            float bvv = bv[gn];
#pragma unroll
            for (int i = 0; i < 4; i++) {
                int gm = m0 + wm + i * 16 + 4 * lg;
#pragma unroll
                for (int jj = 0; jj < 4; jj++) {
                    float val = acc[i][j][jj] + bvv;
                    int m = gm + jj, n = gn;
                    int b = m >> 11, s = m & 2047;
                    int h = n >> 6, dl = n & 63;
                    size_t off = (size_t)(b * 16 + h) * 131072 +
                                 (size_t)(s >> 5) * 2048 + ((s >> 4) & 1) * 1024 +
                                 dl * 16 + (s & 15);
                    Vt[off] = f2bf(val);
                }
            }
        }
        return;
    }

    // ---------------- attn pass 1 ----------------
    int wid = (bid & 7) * 128 + (bid >> 3);
    int qt = wid & 15, bh = wid >> 4;
    int b = bh >> 4, h = bh & 15;
    int qbase = qt * 128 + w * 16;

    const unsigned short* Qr0 = Qp + (size_t)(b * S + qbase + ln) * Dm + h * 64;
    const unsigned short* Qr1 = Qr0 + (size_t)64 * Dm;
    short8 q00 = *(const short8*)&Qr0[8 * lg];
    short8 q01 = *(const short8*)&Qr0[32 + 8 * lg];
    short8 q10 = *(const short8*)&Qr1[8 * lg];
    short8 q11 = *(const short8*)&Qr1[32 + 8 * lg];

    const unsigned short* Kb = Kt + (size_t)bh * 131072;
    const int c0x = (lg ^ (ln & 7)) * 8;
    const int c1x = ((4 + lg) ^ (ln & 7)) * 8;
    const int gb[4] = { ln * 64, 1024 + ln * 64, 2048 + ln * 64, 3072 + ln * 64 };

#define STAGE_K64(it, buf) do { \
    gload_lds16(Kb + (size_t)(it) * 4096 + t * 8, &smem[(buf) * 4096 + w * 512]); \
    gload_lds16(Kb + (size_t)(it) * 4096 + 2048 + t * 8, &smem[(buf) * 4096 + 2048 + w * 512]); } while (0)

    const f32x4 zero = {0.f, 0.f, 0.f, 0.f};
    float se0 = 0.f, se1 = 0.f;
    int cur = 0;
    STAGE_K64(0, 0);
    __syncthreads();
    for (int it = 0; it < 32; ++it) {
        if (it < 31) STAGE_K64(it + 1, cur ^ 1);
        f32x4 s0[4], s1[4];
        __builtin_amdgcn_s_setprio(1);
#pragma unroll
        for (int g = 0; g < 4; g++) {
            short8 ka = *(const short8*)&smem[cur * 4096 + gb[g] + c0x];
            short8 kb = *(const short8*)&smem[cur * 4096 + gb[g] + c1x];
            s0[g] = MFMA32(ka, q00, zero);
            s0[g] = MFMA32(kb, q01, s0[g]);
            s1[g] = MFMA32(ka, q10, zero);
            s1[g] = MFMA32(kb, q11, s1[g]);
        }
        __builtin_amdgcn_s_setprio(0);
#pragma unroll
        for (int g = 0; g < 4; g++) {
#pragma unroll
            for (int j = 0; j < 4; j++) {
                se0 += SEXP(s0[g][j]);
                se1 += SEXP(s1[g][j]);
            }
        }
        __syncthreads();
        cur ^= 1;
    }
    se0 += __shfl_xor(se0, 16); se0 += __shfl_xor(se0, 32);
    se1 += __shfl_xor(se1, 16); se1 += __shfl_xor(se1, 32);
    if (lg == 0) {
        se_buf[bh * 2048 + qbase + ln] = se0;
        se_buf[bh * 2048 + qbase + 64 + ln] = se1;
    }
#undef STAGE_K64
}

// ---------------------------------------------------------------------------
// attn pass 2: recompute scores, write attn (f32, nontemporal), PV.
// Block = (b,h) x 128 q-rows (2 sets). KVBLK=64 double-buffered K+V.
// ---------------------------------------------------------------------------
__global__ __launch_bounds__(256) void attn_pass2(const unsigned short* __restrict__ Qp,
                                                  const unsigned short* __restrict__ Kt,
                                                  const unsigned short* __restrict__ Vt,
                                                  const float* __restrict__ se_buf,
                                                  float* __restrict__ attn_out,
                                                  unsigned short* __restrict__ Ctx) {
    const int S = 2048, Dm = 1024;
    __shared__ unsigned short Ks[2][4096];
    __shared__ unsigned short Vs[2][4096];

    int blk = blockIdx.x;
    int wid = (blk & 7) * 128 + (blk >> 3);
    int qt = wid & 15, bh = wid >> 4;
    int b = bh >> 4, h = bh & 15;
    int t = threadIdx.x, l = t & 63, w = t >> 6;
    int lg = l >> 4, ln = l & 15;
    int qbase = qt * 128 + w * 16;

    const unsigned short* Qr0 = Qp + (size_t)(b * S + qbase + ln) * Dm + h * 64;
    const unsigned short* Qr1 = Qr0 + (size_t)64 * Dm;
    short8 q00 = *(const short8*)&Qr0[8 * lg];
    short8 q01 = *(const short8*)&Qr0[32 + 8 * lg];
    short8 q10 = *(const short8*)&Qr1[8 * lg];
    short8 q11 = *(const short8*)&Qr1[32 + 8 * lg];

    float inv0 = 1.0f / se_buf[bh * 2048 + qbase + ln];
    float inv1 = 1.0f / se_buf[bh * 2048 + qbase + 64 + ln];

    const unsigned short* Kb = Kt + (size_t)bh * 131072;
    const unsigned short* Vb = Vt + (size_t)bh * 131072;
    const int c0x = (lg ^ (ln & 7)) * 8;
    const int c1x = ((4 + lg) ^ (ln & 7)) * 8;
    const int gb[4] = { ln * 64, 1024 + ln * 64, 2048 + ln * 64, 3072 + ln * 64 };

#define STAGE_K64(it, buf) do { \
    gload_lds16(Kb + (size_t)(it) * 4096 + t * 8, &Ks[buf][w * 512]); \
    gload_lds16(Kb + (size_t)(it) * 4096 + 2048 + t * 8, &Ks[buf][2048 + w * 512]); } while (0)
#define STAGE_V64(it, buf) do { \
    gload_lds16(Vb + (size_t)(it) * 4096 + t * 8, &Vs[buf][w * 512]); \
    gload_lds16(Vb + (size_t)(it) * 4096 + 2048 + t * 8, &Vs[buf][2048 + w * 512]); } while (0)

    const f32x4 zero = {0.f, 0.f, 0.f, 0.f};
    f32x4 acc0[4], acc1[4];
#pragma unroll
    for (int i = 0; i < 4; i++) { acc0[i] = zero; acc1[i] = zero; }

    float* Ar0 = attn_out + ((size_t)bh * S + qbase + ln) * S;
    float* Ar1 = Ar0 + (size_t)64 * S;

    int cur = 0;
    STAGE_K64(0, 0);
    STAGE_V64(0, 0);
    __syncthreads();
    for (int it = 0; it < 32; ++it) {
        if (it < 31) { STAGE_K64(it + 1, cur ^ 1); STAGE_V64(it + 1, cur ^ 1); }
        f32x4 s0[4], s1[4];
        __builtin_amdgcn_s_setprio(1);
#pragma unroll
        for (int g = 0; g < 4; g++) {
            short8 ka = *(const short8*)&Ks[cur][gb[g] + c0x];
            short8 kb = *(const short8*)&Ks[cur][gb[g] + c1x];
            s0[g] = MFMA32(ka, q00, zero);
            s0[g] = MFMA32(kb, q01, s0[g]);
            s1[g] = MFMA32(ka, q10, zero);
            s1[g] = MFMA32(kb, q11, s1[g]);
        }
        __builtin_amdgcn_s_setprio(0);

        union { short4b v; unsigned short u[4]; } pf0[4], pf1[4];
#pragma unroll
        for (int g = 0; g < 4; g++) {
            f32x4 pw0, pw1;
#pragma unroll
            for (int j = 0; j < 4; j++) {
                float p0 = SEXP(s0[g][j]) * inv0;
                float p1 = SEXP(s1[g][j]) * inv1;
                pw0[j] = p0; pf0[g].u[j] = f2bf(p0);
                pw1[j] = p1; pf1[g].u[j] = f2bf(p1);
            }
            __builtin_nontemporal_store(pw0, (f32x4*)&Ar0[it * 64 + g * 16 + 4 * lg]);
            __builtin_nontemporal_store(pw1, (f32x4*)&Ar1[it * 64 + g * 16 + 4 * lg]);
        }

        __builtin_amdgcn_s_setprio(1);
#pragma unroll
        for (int db = 0; db < 4; db++) {
            int vbase = (db * 16 + ln) * 16 + 4 * lg;
#pragma unroll
            for (int g = 0; g < 4; g++) {
                short4b vf = *(const short4b*)&Vs[cur][g * 1024 + vbase];
                acc0[db] = MFMA_PV(pf0[g].v, vf, acc0[db]);
                acc1[db] = MFMA_PV(pf1[g].v, vf, acc1[db]);
            }
        }
        __builtin_amdgcn_s_setprio(0);
        __syncthreads();
        cur ^= 1;
    }

#pragma unroll
    for (int db = 0; db < 4; db++)
#pragma unroll
        for (int j = 0; j < 4; j++) {
            Ctx[(size_t)(b * S + qbase + 4 * lg + j) * Dm + h * 64 + db * 16 + ln] =
                f2bf(acc0[db][j]);
            Ctx[(size_t)(b * S + qbase + 64 + 4 * lg + j) * Dm + h * 64 + db * 16 + ln] =
                f2bf(acc1[db][j]);
        }
#undef STAGE_K64
#undef STAGE_V64
}

// ---------------------------------------------------------------------------
// Output projection: out0 = Ctx @ WoT^T + bo, f32 nontemporal out
// ---------------------------------------------------------------------------
__global__ __launch_bounds__(256) void gemm_out(const unsigned short* __restrict__ X,
                                                const unsigned short* __restrict__ Wt,
                                                const float* __restrict__ bias,
                                                float* __restrict__ outp) {
    __shared__ unsigned short As[8192];
    __shared__ unsigned short Bs[8192];
    const int t = threadIdx.x, l = t & 63, w = t >> 6;
    const int lg = l >> 4, ln = l & 15;
    const int wm = (w >> 1) * 64, wn = (w & 1) * 64;
    const int m0 = blockIdx.y * 128, n0 = blockIdx.x * 128;

    const f32x4 zero = {0.f, 0.f, 0.f, 0.f};
    f32x4 acc[4][4];
#pragma unroll
    for (int i = 0; i < 4; i++)
#pragma unroll
        for (int j = 0; j < 4; j++) acc[i][j] = zero;

    gemm_core(X, Wt, As, Bs, m0, n0, 1024, acc);

#pragma unroll
    for (int j = 0; j < 4; j++) {
        int gn = n0 + wn + j * 16 + ln;
        float bvv = bias[gn];
#pragma unroll
        for (int i = 0; i < 4; i++) {
            int gm = m0 + wm + i * 16 + 4 * lg;
#pragma unroll
            for (int jj = 0; jj < 4; jj++)
                __builtin_nontemporal_store(acc[i][j][jj] + bvv,
                                            &outp[(size_t)(gm + jj) * 1024 + gn]);
        }
    }
}

// ---------------------------------------------------------------------------
extern "C" void kernel_launch(void* const* d_in, const int* in_sizes, int n_in,
                              void* d_out, int out_size, void* d_ws, size_t ws_size,
                              hipStream_t stream) {
    const float* query = (const float*)d_in[0];
    const float* key_  = (const float*)d_in[1];
    const float* value = (const float*)d_in[2];
    const float* Wq = (const float*)d_in[4];
    const float* bq = (const float*)d_in[5];
    const float* Wk = (const float*)d_in[6];
    const float* bk = (const float*)d_in[7];
    const float* Wv = (const float*)d_in[8];
    const float* bv = (const float*)d_in[9];
    const float* Wo = (const float*)d_in[10];
    const float* bo = (const float*)d_in[11];

    const size_t BSD = (size_t)4 * 2048 * 1024;
    const size_t DD  = (size_t)1024 * 1024;

    unsigned short* Xq  = (unsigned short*)d_ws;
    unsigned short* Xk  = Xq + BSD;
    unsigned short* Xv  = Xk + BSD;
    unsigned short* Qp  = Xv + BSD;
    unsigned short* Kt  = Qp + BSD;                 // K tiled+swizzled
    unsigned short* Vt  = Kt + BSD;                 // V tiled
    unsigned short* WqT = Vt + BSD;
    unsigned short* WkT = WqT + DD;
    unsigned short* WvT = WkT + DD;
    unsigned short* WoT = WvT + DD;
    float* SE = (float*)(WoT + DD);                 // 64*2048 f32
    unsigned short* Ctx = Xq;                       // reuse (dead after gemm_qk... used after pass2 only)

    float* out0 = (float*)d_out;                    // [B,S,D] f32
    float* attn = out0 + BSD;                       // [B,H,S,S] f32

    dim3 tb(256);

    prep<<<dim3(28672), tb, 0, stream>>>(query, key_, value, Wq, Wk, Wv, Wo,
                                         Xq, Xk, Xv, WqT, WkT, WvT, WoT);

    gemm_qk<<<dim3(8, 64, 2), tb, 0, stream>>>(Xq, Xk, WqT, WkT, bq, bk, Qp, Kt);

    gemmv_pass1<<<dim3(1536), tb, 0, stream>>>(Xv, WvT, bv, Vt, Qp, Kt, SE);

    attn_pass2<<<dim3(1024), tb, 0, stream>>>(Qp, Kt, Vt, SE, attn, Ctx);

    gemm_out<<<dim3(8, 64), tb, 0, stream>>>(Ctx, WoT, bo, out0);
}

// Round 8
// 550.880 us; speedup vs baseline: 1.0105x; 1.0105x over previous
//
#include <hip/hip_runtime.h>
#include <hip/hip_bf16.h>

typedef __attribute__((ext_vector_type(4))) unsigned short u16x4;
typedef __attribute__((ext_vector_type(8))) short short8;
typedef __attribute__((ext_vector_type(4))) short short4b;
typedef __attribute__((ext_vector_type(4))) float f32x4;

__device__ inline unsigned short f2bf(float f) {
    union { float f; unsigned int i; } v; v.f = f;
    unsigned int r = v.i + 0x7fffu + ((v.i >> 16) & 1u);
    return (unsigned short)(r >> 16);
}

// pack 2 f32 -> 2 bf16 in one u32 (v_cvt_pk_bf16_f32 via compiler)
__device__ inline unsigned int pk_bf16(float a, float b) {
    union { __hip_bfloat162 h; unsigned int u; } cv;
    cv.h = __float22bfloat162_rn(float2{a, b});
    return cv.u;
}

#define MFMA_PV(a, b, c) __builtin_amdgcn_mfma_f32_16x16x16bf16_1k((a), (b), (c), 0, 0, 0)
#define MFMA32(a, b, c) __builtin_amdgcn_mfma_f32_16x16x32_bf16((a), (b), (c), 0, 0, 0)

// exp(s*0.125) == exp2(s * 0.125*log2(e))
#define SCL 0.18033688011112042f

__device__ inline void gload_lds16(const unsigned short* g, unsigned short* l) {
    __builtin_amdgcn_global_load_lds(
        (const __attribute__((address_space(1))) void*)g,
        (__attribute__((address_space(3))) void*)l,
        16, 0, 0);
}

// ---------------------------------------------------------------------------
// prep: 3 input converts (f32->bf16) + 4 weight transpose+converts, one launch
// ---------------------------------------------------------------------------
__global__ __launch_bounds__(256) void prep(const float* __restrict__ q,
                                            const float* __restrict__ k,
                                            const float* __restrict__ v,
                                            const float* __restrict__ W0,
                                            const float* __restrict__ W1,
                                            const float* __restrict__ W2,
                                            const float* __restrict__ W3,
                                            unsigned short* __restrict__ Xq,
                                            unsigned short* __restrict__ Xk,
                                            unsigned short* __restrict__ Xv,
                                            unsigned short* __restrict__ O0,
                                            unsigned short* __restrict__ O1,
                                            unsigned short* __restrict__ O2,
                                            unsigned short* __restrict__ O3) {
    __shared__ unsigned short tile[32][33];
    int bid = blockIdx.x;
    if (bid < 24576) {
        const float* in = (bid < 8192) ? q : (bid < 16384) ? k : v;
        unsigned short* out = (bid < 8192) ? Xq : (bid < 16384) ? Xk : Xv;
        int i = (bid & 8191) * 256 + threadIdx.x;
        float4 vv = ((const float4*)in)[i];
        u16x4 o = { f2bf(vv.x), f2bf(vv.y), f2bf(vv.z), f2bf(vv.w) };
        ((u16x4*)out)[i] = o;
    } else {
        int rem = bid - 24576;
        int z = rem >> 10, idx = rem & 1023;
        const float* in = (z == 0) ? W0 : (z == 1) ? W1 : (z == 2) ? W2 : W3;
        unsigned short* out = (z == 0) ? O0 : (z == 1) ? O1 : (z == 2) ? O2 : O3;
        int c0 = (idx & 31) * 32, r0 = (idx >> 5) * 32;
        int x = threadIdx.x & 31, y = threadIdx.x >> 5;
#pragma unroll
        for (int i = 0; i < 4; i++)
            tile[y + i * 8][x] = f2bf(in[(size_t)(r0 + y + i * 8) * 1024 + c0 + x]);
        __syncthreads();
#pragma unroll
        for (int i = 0; i < 4; i++)
            out[(size_t)(c0 + y + i * 8) * 1024 + r0 + x] = tile[x][y + i * 8];
    }
}

// ---------------------------------------------------------------------------
// Shared GEMM core (m97 structure + T2 via pre-swizzled source).
// ---------------------------------------------------------------------------
__device__ __forceinline__ void gemm_core(const unsigned short* __restrict__ X,
                                          const unsigned short* __restrict__ Wt,
                                          unsigned short* As, unsigned short* Bs,
                                          int m0, int n0, int K, f32x4 acc[4][4]) {
    const int t = threadIdx.x;
    const int l = t & 63, w = t >> 6;
    const int lg = l >> 4, ln = l & 15;
    const int wm = (w >> 1) * 64, wn = (w & 1) * 64;

    int sr[4], sc[4];
#pragma unroll
    for (int i = 0; i < 4; i++) {
        int pos = i * 2048 + t * 8;
        sr[i] = pos >> 6;
        int c8 = (pos >> 3) & 7;
        sc[i] = (c8 ^ (sr[i] & 7)) * 8;
    }

    for (int k0 = 0; k0 < K; k0 += 64) {
#pragma unroll
        for (int i = 0; i < 4; i++)
            gload_lds16(&X[(size_t)(m0 + sr[i]) * K + k0 + sc[i]], &As[i * 2048 + w * 512]);
#pragma unroll
        for (int i = 0; i < 4; i++)
            gload_lds16(&Wt[(size_t)(n0 + sr[i]) * K + k0 + sc[i]], &Bs[i * 2048 + w * 512]);
        __syncthreads();
#pragma unroll
        for (int kk = 0; kk < 2; kk++) {
            short8 af[4], bfr[4];
#pragma unroll
            for (int i = 0; i < 4; i++) {
                int sl = (((kk << 2) | lg) ^ (ln & 7)) * 8;
                af[i]  = *(const short8*)&As[(wm + i * 16 + ln) * 64 + sl];
                bfr[i] = *(const short8*)&Bs[(wn + i * 16 + ln) * 64 + sl];
            }
#pragma unroll
            for (int i = 0; i < 4; i++)
#pragma unroll
                for (int j = 0; j < 4; j++)
                    acc[i][j] = MFMA32(af[i], bfr[j], acc[i][j]);
        }
        __syncthreads();
    }
}

// ---------------------------------------------------------------------------
// Q-GEMM (z=0, linear bf16 out) + K-GEMM (z=1, KTILED+swizzle out)
// ---------------------------------------------------------------------------
__global__ __launch_bounds__(256) void gemm_qk(const unsigned short* __restrict__ Xq,
                                               const unsigned short* __restrict__ Xk,
                                               const unsigned short* __restrict__ WqT,
                                               const unsigned short* __restrict__ WkT,
                                               const float* __restrict__ bq,
                                               const float* __restrict__ bk,
                                               unsigned short* __restrict__ Qp,
                                               unsigned short* __restrict__ Kt) {
    __shared__ unsigned short As[8192];
    __shared__ unsigned short Bs[8192];
    const int z = blockIdx.z;
    const unsigned short* X = z ? Xk : Xq;
    const unsigned short* Wt = z ? WkT : WqT;
    const float* bias = z ? bk : bq;
    const int t = threadIdx.x, l = t & 63, w = t >> 6;
    const int lg = l >> 4, ln = l & 15;
    const int wm = (w >> 1) * 64, wn = (w & 1) * 64;
    const int m0 = blockIdx.y * 128, n0 = blockIdx.x * 128;

    const f32x4 zero = {0.f, 0.f, 0.f, 0.f};
    f32x4 acc[4][4];
#pragma unroll
    for (int i = 0; i < 4; i++)
#pragma unroll
        for (int j = 0; j < 4; j++) acc[i][j] = zero;

    gemm_core(X, Wt, As, Bs, m0, n0, 1024, acc);

#pragma unroll
    for (int j = 0; j < 4; j++) {
        int gn = n0 + wn + j * 16 + ln;
        float bvv = bias[gn];
#pragma unroll
        for (int i = 0; i < 4; i++) {
            int gm = m0 + wm + i * 16 + 4 * lg;
#pragma unroll
            for (int jj = 0; jj < 4; jj++) {
                float val = acc[i][j][jj] + bvv;
                int m = gm + jj, n = gn;
                if (z) {
                    int b = m >> 11, s = m & 2047;
                    int itk = s >> 5, r = s & 31;
                    int h = n >> 6, dl = n & 63;
                    int cst = (dl >> 3) ^ (r & 7);
                    size_t off = (size_t)(b * 16 + h) * 131072 +
                                 (size_t)itk * 2048 + r * 64 + cst * 8 + (dl & 7);
                    Kt[off] = f2bf(val);
                } else {
                    Qp[(size_t)m * 1024 + n] = f2bf(val);
                }
            }
        }
    }
}

// ---------------------------------------------------------------------------
// V-GEMM, VTILED epilogue (standalone launch, grid (8,64))
// ---------------------------------------------------------------------------
__global__ __launch_bounds__(256) void gemm_v(const unsigned short* __restrict__ Xv,
                                              const unsigned short* __restrict__ WvT,
                                              const float* __restrict__ bv,
                                              unsigned short* __restrict__ Vt) {
    __shared__ unsigned short As[8192];
    __shared__ unsigned short Bs[8192];
    const int t = threadIdx.x, l = t & 63, w = t >> 6;
    const int lg = l >> 4, ln = l & 15;
    const int wm = (w >> 1) * 64, wn = (w & 1) * 64;
    const int m0 = blockIdx.y * 128, n0 = blockIdx.x * 128;

    const f32x4 zero = {0.f, 0.f, 0.f, 0.f};
    f32x4 acc[4][4];
#pragma unroll
    for (int i = 0; i < 4; i++)
#pragma unroll
        for (int j = 0; j < 4; j++) acc[i][j] = zero;

    gemm_core(Xv, WvT, As, Bs, m0, n0, 1024, acc);

#pragma unroll
    for (int j = 0; j < 4; j++) {
        int gn = n0 + wn + j * 16 + ln;
        float bvv = bv[gn];
#pragma unroll
        for (int i = 0; i < 4; i++) {
            int gm = m0 + wm + i * 16 + 4 * lg;
#pragma unroll
            for (int jj = 0; jj < 4; jj++) {
                float val = acc[i][j][jj] + bvv;
                int m = gm + jj, n = gn;
                int b = m >> 11, s = m & 2047;
                int h = n >> 6, dl = n & 63;
                size_t off = (size_t)(b * 16 + h) * 131072 +
                             (size_t)(s >> 5) * 2048 + ((s >> 4) & 1) * 1024 +
                             dl * 16 + (s & 15);
                Vt[off] = f2bf(val);
            }
        }
    }
}

// ---------------------------------------------------------------------------
// attn pass 1: per-q-row lse = log2(sum exp2(s*SCL)). Block = (b,h) x 128
// q-rows (2 sets of 64). KVBLK=64 double-buffered. 16 KB LDS.
// ---------------------------------------------------------------------------
__global__ __launch_bounds__(256) void attn_pass1(const unsigned short* __restrict__ Qp,
                                                  const unsigned short* __restrict__ Kt,
                                                  float* __restrict__ lse_buf) {
    const int S = 2048, Dm = 1024;
    __shared__ unsigned short Ks[2][4096];

    int blk = blockIdx.x;
    int wid = (blk & 7) * 128 + (blk >> 3);
    int qt = wid & 15, bh = wid >> 4;
    int b = bh >> 4, h = bh & 15;
    int t = threadIdx.x, l = t & 63, w = t >> 6;
    int lg = l >> 4, ln = l & 15;
    int qbase = qt * 128 + w * 16;

    const unsigned short* Qr0 = Qp + (size_t)(b * S + qbase + ln) * Dm + h * 64;
    const unsigned short* Qr1 = Qr0 + (size_t)64 * Dm;
    short8 q00 = *(const short8*)&Qr0[8 * lg];
    short8 q01 = *(const short8*)&Qr0[32 + 8 * lg];
    short8 q10 = *(const short8*)&Qr1[8 * lg];
    short8 q11 = *(const short8*)&Qr1[32 + 8 * lg];

    const unsigned short* Kb = Kt + (size_t)bh * 131072;
    const int c0x = (lg ^ (ln & 7)) * 8;
    const int c1x = ((4 + lg) ^ (ln & 7)) * 8;
    const int gb[4] = { ln * 64, 1024 + ln * 64, 2048 + ln * 64, 3072 + ln * 64 };

#define STAGE_K64(it, buf) do { \
    gload_lds16(Kb + (size_t)(it) * 4096 + t * 8, &Ks[buf][w * 512]); \
    gload_lds16(Kb + (size_t)(it) * 4096 + 2048 + t * 8, &Ks[buf][2048 + w * 512]); } while (0)

    const f32x4 zero = {0.f, 0.f, 0.f, 0.f};
    float se0 = 0.f, se1 = 0.f;
    int cur = 0;
    STAGE_K64(0, 0);
    __syncthreads();
    for (int it = 0; it < 32; ++it) {
        if (it < 31) STAGE_K64(it + 1, cur ^ 1);
        f32x4 s0[4], s1[4];
        __builtin_amdgcn_s_setprio(1);
#pragma unroll
        for (int g = 0; g < 4; g++) {
            short8 ka = *(const short8*)&Ks[cur][gb[g] + c0x];
            short8 kb = *(const short8*)&Ks[cur][gb[g] + c1x];
            s0[g] = MFMA32(ka, q00, zero);
            s0[g] = MFMA32(kb, q01, s0[g]);
            s1[g] = MFMA32(ka, q10, zero);
            s1[g] = MFMA32(kb, q11, s1[g]);
        }
        __builtin_amdgcn_s_setprio(0);
#pragma unroll
        for (int g = 0; g < 4; g++) {
#pragma unroll
            for (int j = 0; j < 4; j++) {
                se0 += exp2f(s0[g][j] * SCL);
                se1 += exp2f(s1[g][j] * SCL);
            }
        }
        __syncthreads();
        cur ^= 1;
    }
    se0 += __shfl_xor(se0, 16); se0 += __shfl_xor(se0, 32);
    se1 += __shfl_xor(se1, 16); se1 += __shfl_xor(se1, 32);
    if (lg == 0) {
        lse_buf[bh * 2048 + qbase + ln] = log2f(se0);
        lse_buf[bh * 2048 + qbase + 64 + ln] = log2f(se1);
    }
#undef STAGE_K64
}

// ---------------------------------------------------------------------------
// attn pass 2: p = exp2(fma(s, SCL, -lse)); write attn f32 NT; PV.
// Block = (b,h) x 128 q-rows (2 sets). KVBLK=64 double-buffered K+V.
// ---------------------------------------------------------------------------
__global__ __launch_bounds__(256) void attn_pass2(const unsigned short* __restrict__ Qp,
                                                  const unsigned short* __restrict__ Kt,
                                                  const unsigned short* __restrict__ Vt,
                                                  const float* __restrict__ lse_buf,
                                                  float* __restrict__ attn_out,
                                                  unsigned short* __restrict__ Ctx) {
    const int S = 2048, Dm = 1024;
    __shared__ unsigned short Ks[2][4096];
    __shared__ unsigned short Vs[2][4096];

    int blk = blockIdx.x;
    int wid = (blk & 7) * 128 + (blk >> 3);
    int qt = wid & 15, bh = wid >> 4;
    int b = bh >> 4, h = bh & 15;
    int t = threadIdx.x, l = t & 63, w = t >> 6;
    int lg = l >> 4, ln = l & 15;
    int qbase = qt * 128 + w * 16;

    const unsigned short* Qr0 = Qp + (size_t)(b * S + qbase + ln) * Dm + h * 64;
    const unsigned short* Qr1 = Qr0 + (size_t)64 * Dm;
    short8 q00 = *(const short8*)&Qr0[8 * lg];
    short8 q01 = *(const short8*)&Qr0[32 + 8 * lg];
    short8 q10 = *(const short8*)&Qr1[8 * lg];
    short8 q11 = *(const short8*)&Qr1[32 + 8 * lg];

    float nlse0 = -lse_buf[bh * 2048 + qbase + ln];
    float nlse1 = -lse_buf[bh * 2048 + qbase + 64 + ln];

    const unsigned short* Kb = Kt + (size_t)bh * 131072;
    const unsigned short* Vb = Vt + (size_t)bh * 131072;
    const int c0x = (lg ^ (ln & 7)) * 8;
    const int c1x = ((4 + lg) ^ (ln & 7)) * 8;
    const int gb[4] = { ln * 64, 1024 + ln * 64, 2048 + ln * 64, 3072 + ln * 64 };

#define STAGE_K64(it, buf) do { \
    gload_lds16(Kb + (size_t)(it) * 4096 + t * 8, &Ks[buf][w * 512]); \
    gload_lds16(Kb + (size_t)(it) * 4096 + 2048 + t * 8, &Ks[buf][2048 + w * 512]); } while (0)
#define STAGE_V64(it, buf) do { \
    gload_lds16(Vb + (size_t)(it) * 4096 + t * 8, &Vs[buf][w * 512]); \
    gload_lds16(Vb + (size_t)(it) * 4096 + 2048 + t * 8, &Vs[buf][2048 + w * 512]); } while (0)

    const f32x4 zero = {0.f, 0.f, 0.f, 0.f};
    f32x4 acc0[4], acc1[4];
#pragma unroll
    for (int i = 0; i < 4; i++) { acc0[i] = zero; acc1[i] = zero; }

    float* Ar0 = attn_out + ((size_t)bh * S + qbase + ln) * S;
    float* Ar1 = Ar0 + (size_t)64 * S;

    int cur = 0;
    STAGE_K64(0, 0);
    STAGE_V64(0, 0);
    __syncthreads();
    for (int it = 0; it < 32; ++it) {
        if (it < 31) { STAGE_K64(it + 1, cur ^ 1); STAGE_V64(it + 1, cur ^ 1); }
        f32x4 s0[4], s1[4];
        __builtin_amdgcn_s_setprio(1);
#pragma unroll
        for (int g = 0; g < 4; g++) {
            short8 ka = *(const short8*)&Ks[cur][gb[g] + c0x];
            short8 kb = *(const short8*)&Ks[cur][gb[g] + c1x];
            s0[g] = MFMA32(ka, q00, zero);
            s0[g] = MFMA32(kb, q01, s0[g]);
            s1[g] = MFMA32(ka, q10, zero);
            s1[g] = MFMA32(kb, q11, s1[g]);
        }
        __builtin_amdgcn_s_setprio(0);

        union { short4b v; unsigned int u2[2]; } pf0[4], pf1[4];
#pragma unroll
        for (int g = 0; g < 4; g++) {
            f32x4 pw0, pw1;
#pragma unroll
            for (int j = 0; j < 4; j++) {
                pw0[j] = exp2f(fmaf(s0[g][j], SCL, nlse0));
                pw1[j] = exp2f(fmaf(s1[g][j], SCL, nlse1));
            }
            pf0[g].u2[0] = pk_bf16(pw0[0], pw0[1]);
            pf0[g].u2[1] = pk_bf16(pw0[2], pw0[3]);
            pf1[g].u2[0] = pk_bf16(pw1[0], pw1[1]);
            pf1[g].u2[1] = pk_bf16(pw1[2], pw1[3]);
            __builtin_nontemporal_store(pw0, (f32x4*)&Ar0[it * 64 + g * 16 + 4 * lg]);
            __builtin_nontemporal_store(pw1, (f32x4*)&Ar1[it * 64 + g * 16 + 4 * lg]);
        }

        __builtin_amdgcn_s_setprio(1);
#pragma unroll
        for (int db = 0; db < 4; db++) {
            int vbase = (db * 16 + ln) * 16 + 4 * lg;
#pragma unroll
            for (int g = 0; g < 4; g++) {
                short4b vf = *(const short4b*)&Vs[cur][g * 1024 + vbase];
                acc0[db] = MFMA_PV(pf0[g].v, vf, acc0[db]);
                acc1[db] = MFMA_PV(pf1[g].v, vf, acc1[db]);
            }
        }
        __builtin_amdgcn_s_setprio(0);
        __syncthreads();
        cur ^= 1;
    }

#pragma unroll
    for (int db = 0; db < 4; db++)
#pragma unroll
        for (int j = 0; j < 4; j++) {
            Ctx[(size_t)(b * S + qbase + 4 * lg + j) * Dm + h * 64 + db * 16 + ln] =
                f2bf(acc0[db][j]);
            Ctx[(size_t)(b * S + qbase + 64 + 4 * lg + j) * Dm + h * 64 + db * 16 + ln] =
                f2bf(acc1[db][j]);
        }
#undef STAGE_K64
#undef STAGE_V64
}

// ---------------------------------------------------------------------------
// Output projection: out0 = Ctx @ WoT^T + bo, f32 nontemporal out
// ---------------------------------------------------------------------------
__global__ __launch_bounds__(256) void gemm_out(const unsigned short* __restrict__ X,
                                                const unsigned short* __restrict__ Wt,
                                                const float* __restrict__ bias,
                                                float* __restrict__ outp) {
    __shared__ unsigned short As[8192];
    __shared__ unsigned short Bs[8192];
    const int t = threadIdx.x, l = t & 63, w = t >> 6;
    const int lg = l >> 4, ln = l & 15;
    const int wm = (w >> 1) * 64, wn = (w & 1) * 64;
    const int m0 = blockIdx.y * 128, n0 = blockIdx.x * 128;

    const f32x4 zero = {0.f, 0.f, 0.f, 0.f};
    f32x4 acc[4][4];
#pragma unroll
    for (int i = 0; i < 4; i++)
#pragma unroll
        for (int j = 0; j < 4; j++) acc[i][j] = zero;

    gemm_core(X, Wt, As, Bs, m0, n0, 1024, acc);

#pragma unroll
    for (int j = 0; j < 4; j++) {
        int gn = n0 + wn + j * 16 + ln;
        float bvv = bias[gn];
#pragma unroll
        for (int i = 0; i < 4; i++) {
            int gm = m0 + wm + i * 16 + 4 * lg;
#pragma unroll
            for (int jj = 0; jj < 4; jj++)
                __builtin_nontemporal_store(acc[i][j][jj] + bvv,
                                            &outp[(size_t)(gm + jj) * 1024 + gn]);
        }
    }
}

// ---------------------------------------------------------------------------
extern "C" void kernel_launch(void* const* d_in, const int* in_sizes, int n_in,
                              void* d_out, int out_size, void* d_ws, size_t ws_size,
                              hipStream_t stream) {
    const float* query = (const float*)d_in[0];
    const float* key_  = (const float*)d_in[1];
    const float* value = (const float*)d_in[2];
    const float* Wq = (const float*)d_in[4];
    const float* bq = (const float*)d_in[5];
    const float* Wk = (const float*)d_in[6];
    const float* bk = (const float*)d_in[7];
    const float* Wv = (const float*)d_in[8];
    const float* bv = (const float*)d_in[9];
    const float* Wo = (const float*)d_in[10];
    const float* bo = (const float*)d_in[11];

    const size_t BSD = (size_t)4 * 2048 * 1024;
    const size_t DD  = (size_t)1024 * 1024;

    unsigned short* Xq  = (unsigned short*)d_ws;
    unsigned short* Xk  = Xq + BSD;
    unsigned short* Xv  = Xk + BSD;
    unsigned short* Qp  = Xv + BSD;
    unsigned short* Kt  = Qp + BSD;                 // K tiled+swizzled
    unsigned short* Vt  = Kt + BSD;                 // V tiled
    unsigned short* WqT = Vt + BSD;
    unsigned short* WkT = WqT + DD;
    unsigned short* WvT = WkT + DD;
    unsigned short* WoT = WvT + DD;
    float* LSE = (float*)(WoT + DD);                // 64*2048 f32
    unsigned short* Ctx = Xq;                       // dead after gemm_qk

    float* out0 = (float*)d_out;                    // [B,S,D] f32
    float* attn = out0 + BSD;                       // [B,H,S,S] f32

    dim3 tb(256);

    prep<<<dim3(28672), tb, 0, stream>>>(query, key_, value, Wq, Wk, Wv, Wo,
                                         Xq, Xk, Xv, WqT, WkT, WvT, WoT);

    gemm_qk<<<dim3(8, 64, 2), tb, 0, stream>>>(Xq, Xk, WqT, WkT, bq, bk, Qp, Kt);

    attn_pass1<<<dim3(1024), tb, 0, stream>>>(Qp, Kt, LSE);

    gemm_v<<<dim3(8, 64), tb, 0, stream>>>(Xv, WvT, bv, Vt);

    attn_pass2<<<dim3(1024), tb, 0, stream>>>(Qp, Kt, Vt, LSE, attn, Ctx);

    gemm_out<<<dim3(8, 64), tb, 0, stream>>>(Ctx, WoT, bo, out0);
}